// Round 1
// baseline (48.707 us; speedup 1.0000x reference)
//
#include <hip/hip_runtime.h>

#define MARGIN 0.3f
#define ANCHOR 0.5f
#define EPS    1e-8f
#define BJ     256

// ---------------- kernel 0: zero the accumulators ----------------
__global__ void init_acc(double* total, unsigned long long* cnt) {
    *total = 0.0;
    *cnt   = 0ull;
}

// ---------------- kernel 1: s_q and quality ----------------
// One wave (64 lanes) per row of d_embs. D assumed multiple of 1024 layout:
// lane reads float4 at [lane*4 + it*256], it = 0..D/256-1.
__global__ __launch_bounds__(256) void sq_kernel(
        const float* __restrict__ q, const float* __restrict__ d,
        const float* __restrict__ rates,
        float* __restrict__ sq, float* __restrict__ qual,
        int N, int D) {
    int wave = (blockIdx.x * blockDim.x + threadIdx.x) >> 6;
    int lane = threadIdx.x & 63;
    if (wave >= N) return;
    const float* row = d + (size_t)wave * (size_t)D;

    float dot = 0.f, dn = 0.f, qn = 0.f;
    for (int it = lane * 4; it < D; it += 256) {
        float4 dv = *(const float4*)(row + it);
        float4 qv = *(const float4*)(q + it);
        dot += dv.x * qv.x + dv.y * qv.y + dv.z * qv.z + dv.w * qv.w;
        dn  += dv.x * dv.x + dv.y * dv.y + dv.z * dv.z + dv.w * dv.w;
        qn  += qv.x * qv.x + qv.y * qv.y + qv.z * qv.z + qv.w * qv.w;
    }
    #pragma unroll
    for (int off = 32; off >= 1; off >>= 1) {
        dot += __shfl_xor(dot, off);
        dn  += __shfl_xor(dn,  off);
        qn  += __shfl_xor(qn,  off);
    }
    if (lane == 0) {
        float den = fmaxf(sqrtf(dn) * sqrtf(qn), EPS);
        sq[wave]   = dot / den;
        qual[wave] = fabsf(rates[wave] - ANCHOR);
    }
}

// ---------------- kernel 2: N^2 pair reduction ----------------
// grid = (N/256, N/BJ). Thread owns i = blockIdx.x*256 + tid (registers),
// loops the j-tile staged in LDS (uniform -> broadcast reads).
__global__ __launch_bounds__(256) void pair_kernel(
        const float* __restrict__ sq, const float* __restrict__ qual,
        int N, double* __restrict__ total, unsigned long long* __restrict__ cnt) {
    __shared__ float s_sq[BJ];
    __shared__ float s_q[BJ];

    int tid = threadIdx.x;
    int i   = blockIdx.x * blockDim.x + tid;
    int j0  = blockIdx.y * BJ;

    if (tid < BJ) {
        s_sq[tid] = sq[j0 + tid];
        s_q[tid]  = qual[j0 + tid];
    }
    __syncthreads();

    float my_sq = (i < N) ? sq[i]   : 0.f;
    float my_q  = (i < N) ? qual[i] : -1.f;   // quality >= 0, so -1 masks all pairs off

    float sum = 0.f;
    unsigned int c = 0;
    #pragma unroll 4
    for (int j = 0; j < BJ; ++j) {
        bool  m = my_q > s_q[j];
        float v = fmaxf(MARGIN + s_sq[j] - my_sq, 0.f);
        sum += m ? v : 0.f;
        c   += m ? 1u : 0u;
    }

    // wave butterfly reduce
    #pragma unroll
    for (int off = 32; off >= 1; off >>= 1) {
        sum += __shfl_xor(sum, off);
        c   += __shfl_xor(c,   off);
    }
    __shared__ double       bsum[4];
    __shared__ unsigned int bcnt[4];
    int w = tid >> 6;
    if ((tid & 63) == 0) { bsum[w] = (double)sum; bcnt[w] = c; }
    __syncthreads();
    if (tid == 0) {
        double        t  = bsum[0] + bsum[1] + bsum[2] + bsum[3];
        unsigned int  cc = bcnt[0] + bcnt[1] + bcnt[2] + bcnt[3];
        atomicAdd(total, t);
        atomicAdd(cnt, (unsigned long long)cc);
    }
}

// ---------------- kernel 3: finalize ----------------
__global__ void finalize(const double* __restrict__ total,
                         const unsigned long long* __restrict__ cnt,
                         float* __restrict__ out) {
    unsigned long long c = *cnt;
    if (c < 1ull) c = 1ull;
    out[0] = (float)(*total / (double)c);
}

extern "C" void kernel_launch(void* const* d_in, const int* in_sizes, int n_in,
                              void* d_out, int out_size, void* d_ws, size_t ws_size,
                              hipStream_t stream) {
    const float* q_emb  = (const float*)d_in[0];
    const float* d_embs = (const float*)d_in[1];
    // d_in[2] = c_emb: computed-but-unused in the reference; skip entirely.
    const float* rates  = (const float*)d_in[3];

    int D = in_sizes[0];
    int N = in_sizes[3];

    float*              sq    = (float*)d_ws;
    float*              qual  = sq + N;
    double*             total = (double*)(qual + N);          // 8-byte aligned (2N floats)
    unsigned long long* cnt   = (unsigned long long*)(total + 1);
    float*              out   = (float*)d_out;

    init_acc<<<1, 1, 0, stream>>>(total, cnt);

    int rows_per_block = 256 / 64;                            // 4 waves/block
    sq_kernel<<<(N + rows_per_block - 1) / rows_per_block, 256, 0, stream>>>(
        q_emb, d_embs, rates, sq, qual, N, D);

    dim3 grid((N + 255) / 256, (N + BJ - 1) / BJ);
    pair_kernel<<<grid, 256, 0, stream>>>(sq, qual, N, total, cnt);

    finalize<<<1, 1, 0, stream>>>(total, cnt, out);
}